// Round 12
// baseline (161.605 us; speedup 1.0000x reference)
//
#include <hip/hip_runtime.h>
#include <hip/hip_fp16.h>
#include <math.h>

#define TH 256

typedef __attribute__((ext_vector_type(8))) short short8;
typedef __attribute__((ext_vector_type(4))) float floatx4;

// ---- LDS layout (shorts). Per-wave PRIVATE regions -> barrier-free main body.
// Per wave (stride 3744): p1 [0,2356) ; scratch [2360,3736):
//   x (1090, dead after conv1) -> p2 848 | h1 272 | h2 208 | log 48
// Shared (read-only after the single barrier): BT 2688 @ 14976, W1B 300 @ 17664.
#define WV_STRIDE 3744
#define SCR_OFF   2360
#define BT_S      14976
#define W1B_U     8832        // uint index (short 17664)
#define LDS_F     8984        // 35936 B -> 4 blocks/CU

static __device__ __forceinline__ unsigned short f2bf(float x) {
    union { float f; unsigned u; } v; v.f = x;
    return (unsigned short)((v.u + 0x7FFFu + ((v.u >> 16) & 1u)) >> 16);   // RNE
}
static __device__ __forceinline__ __half2 uash2(unsigned u) {
    union { unsigned u; __half2 h; } v; v.u = u; return v.h;
}
static __device__ __forceinline__ unsigned bfpack(unsigned hi, unsigned lo) {
    return __builtin_amdgcn_perm(hi, lo, 0x07060302u);   // 1x v_perm_b32 truncation
}
// weights row[kb..kb+7] -> bf16 frag; per-quad clamp keeps loads in bounds at the
// K tail (matching A slots are zero-padded).
static __device__ __forceinline__ short8 load_bf8t(const float* row, int kb, int K) {
    int b0 = (kb + 4 <= K) ? kb : (K - 8);
    int b1 = (kb + 8 <= K) ? (kb + 4) : (K - 8);
    uint4 w0 = *(const uint4*)(row + b0);
    uint4 w1 = *(const uint4*)(row + b1);
    union { int4 i; short8 s; } r;
    r.i.x = (int)bfpack(w0.y, w0.x);
    r.i.y = (int)bfpack(w0.w, w0.z);
    r.i.z = (int)bfpack(w1.y, w1.x);
    r.i.w = (int)bfpack(w1.w, w1.z);
    return r.s;
}

// NOTE: no min-waves arg (round 3: VGPR clamp -> scratch spill storm).
__global__ __launch_bounds__(TH) void lenet_kernel(
    const float* __restrict__ x,
    const float* __restrict__ w1,
    const float* __restrict__ w2g,
    const float* __restrict__ fw1,
    const float* __restrict__ fw2,
    const float* __restrict__ fc3w,
    const float* __restrict__ fc3b,
    float* __restrict__ out)
{
    __shared__ __align__(16) float sf[LDS_F];
    short* sh = (short*)sf;
    unsigned* su = (unsigned*)sf;
    const int* p1i = (const int*)sf;

    const int tid  = threadIdx.x;
    const int blk  = blockIdx.x;
    const int lane = tid & 63;
    const int wid  = tid >> 6;
    const int g    = lane >> 4;     // k-group selector of MFMA frags
    const int cn   = lane & 15;     // row(A)/col(B) selector

    // per-wave region bases (shorts)
    const int P1w  = wid * WV_STRIDE;
    const int Xw   = P1w + SCR_OFF;
    const int P2w  = Xw;                   // aliases x (dead after conv1)
    const int H1w  = P2w + 848;
    const int H2w  = H1w + 272;
    const int LOGf = (H2w + 208) >> 1;     // float index

    const size_t imgbase = (size_t)blk * 8 + (size_t)wid * 2;

    // ---- prefetch img0 into registers (overlaps weight staging + barrier) ----
    float4 xreg[4];
    {
        const float4* xg = (const float4*)(x + imgbase * 1024);
        #pragma unroll
        for (int j = 0; j < 4; ++j) xreg[j] = xg[lane + j * 64];
    }

    // ---- shared weight staging: the ONLY barrier in the kernel ----
    for (int e = tid; e < 150; e += TH)
        ((__half2*)(su + W1B_U))[e] = __half2half2(__float2half(w1[e]));
    // Bt[oc][ky*32 + r], r = dx*6+ic (<30), zero-pad r=30,31
    for (int e = tid; e < 2560; e += TH) {
        int oc = e / 160, kk = e - oc * 160;
        int s = kk >> 5, r = kk & 31;
        float v = 0.f;
        if (r < 30) v = w2g[oc * 150 + (r % 6) * 25 + s * 5 + (r / 6)];
        sh[BT_S + oc * 168 + kk] = (short)f2bf(v);
    }
    __syncthreads();

    // ======== per-wave pipeline from here: NO cross-wave deps, NO barriers ========

    // ---- conv1 (packed fp16 VALU), 2 images sequentially ----
    for (int img = 0; img < 2; ++img) {
        #pragma unroll
        for (int j = 0; j < 4; ++j) {
            int e = lane + j * 64;
            float4 v = xreg[j];
            int y = e >> 3, k4 = e & 7;
            // row stride 34 halfs (17 words, odd) -> conflict-free conv1 reads
            int off = Xw + y * 34 + k4 * 4;
            *(__half2*)(sh + off)     = __floats2half2_rn(v.x, v.y);
            *(__half2*)(sh + off + 2) = __floats2half2_rn(v.z, v.w);
        }
        if (img == 0) {   // T14: issue img1 loads now; latency hides under img0 compute
            const float4* xg = (const float4*)(x + (imgbase + 1) * 1024);
            #pragma unroll
            for (int j = 0; j < 4; ++j) xreg[j] = xg[lane + j * 64];
        }
        for (int p = 0; p < 3; ++p) {
            int t = p * 64 + lane;
            if (t < 168) {
                int c = t % 6, q = t / 6;
                int i = q >> 1, hf = q & 1;
                const __half2* wb = (const __half2*)(su + W1B_U) + c * 25;
                const int xbase = Xw + hf * 14;

                __half2 acc0[7], acc1[7];
                #pragma unroll
                for (int j = 0; j < 7; ++j) { acc0[j] = uash2(0u); acc1[j] = uash2(0u); }
                __half2 wprev[5];
                #pragma unroll
                for (int tt = 0; tt < 6; ++tt) {
                    unsigned u[9];
                    const unsigned* rp = (const unsigned*)(sh + xbase + (2 * i + tt) * 34);
                    #pragma unroll
                    for (int qq = 0; qq < 9; ++qq) u[qq] = rp[qq];
                    __half2 p0[9], p1[8];
                    #pragma unroll
                    for (int qq = 0; qq < 9; ++qq) p0[qq] = uash2(u[qq]);
                    #pragma unroll
                    for (int qq = 0; qq < 8; ++qq)
                        p1[qq] = uash2(__builtin_amdgcn_perm(u[qq + 1], u[qq], 0x05040302u));

                    if (tt < 5) {
                        __half2 wc[5];
                        #pragma unroll
                        for (int kx = 0; kx < 5; ++kx) wc[kx] = wb[tt * 5 + kx];
                        #pragma unroll
                        for (int j = 0; j < 7; ++j) {
                            acc0[j] = __hfma2(p0[j],     wc[0], acc0[j]);
                            acc0[j] = __hfma2(p1[j],     wc[1], acc0[j]);
                            acc0[j] = __hfma2(p0[j + 1], wc[2], acc0[j]);
                            acc0[j] = __hfma2(p1[j + 1], wc[3], acc0[j]);
                            acc0[j] = __hfma2(p0[j + 2], wc[4], acc0[j]);
                        }
                        if (tt >= 1) {
                            #pragma unroll
                            for (int j = 0; j < 7; ++j) {
                                acc1[j] = __hfma2(p0[j],     wprev[0], acc1[j]);
                                acc1[j] = __hfma2(p1[j],     wprev[1], acc1[j]);
                                acc1[j] = __hfma2(p0[j + 1], wprev[2], acc1[j]);
                                acc1[j] = __hfma2(p1[j + 1], wprev[3], acc1[j]);
                                acc1[j] = __hfma2(p0[j + 2], wprev[4], acc1[j]);
                            }
                        }
                        #pragma unroll
                        for (int kx = 0; kx < 5; ++kx) wprev[kx] = wc[kx];
                    } else {    // tt == 5: acc1 only, with w row 4 (in wprev)
                        #pragma unroll
                        for (int j = 0; j < 7; ++j) {
                            acc1[j] = __hfma2(p0[j],     wprev[0], acc1[j]);
                            acc1[j] = __hfma2(p1[j],     wprev[1], acc1[j]);
                            acc1[j] = __hfma2(p0[j + 1], wprev[2], acc1[j]);
                            acc1[j] = __hfma2(p1[j + 1], wprev[3], acc1[j]);
                            acc1[j] = __hfma2(p0[j + 2], wprev[4], acc1[j]);
                        }
                    }
                }
                short* dst = sh + P1w + img * 1178 + i * 84 + hf * 42 + c;
                #pragma unroll
                for (int j = 0; j < 7; ++j) {
                    float a0l = __half2float(__low2half(acc0[j]));
                    float a0h = __half2float(__high2half(acc0[j]));
                    float a1l = __half2float(__low2half(acc1[j]));
                    float a1h = __half2float(__high2half(acc1[j]));
                    float v = fmaxf(fmaxf(fmaxf(a0l, a0h), fmaxf(a1l, a1h)), 0.f);
                    dst[j * 6] = (short)f2bf(v);
                }
            }
        }
    }

    // ---- pad zeros for p2/h1/h2 K-tails (x region now dead; wave-local order) ----
    if (lane < 48) { int im = lane / 24; sh[P2w + im * 424 + 400 + (lane - im * 24)] = 0; }
    if (lane < 32) { sh[H1w + (lane >> 4) * 136 + 120 + (lane & 15)] = 0; }
    if (lane < 40) { int im = lane / 20; sh[H2w + im * 104 + 84 + (lane - im * 20)] = 0; }

    // ---- conv2 via MFMA (per-wave): M rows = 2 img x 2 dy (periodic), N=16 oc ----
    {
        short8 Breg[5];
        #pragma unroll
        for (int s = 0; s < 5; ++s)
            Breg[s] = *(const short8*)(sh + BT_S + cn * 168 + s * 32 + 8 * g);

        const int aimg = cn & 1;          // A row -> img (periodic over rows)
        const int ady  = (cn >> 1) & 1;   // A row -> pool dy

        for (int w = 0; w < 25; ++w) {
            int i = w / 5, jx = w - 5 * i;
            floatx4 a0 = {0.f,0.f,0.f,0.f}, a1 = {0.f,0.f,0.f,0.f};
            #pragma unroll
            for (int s = 0; s < 5; ++s) {
                #pragma unroll
                for (int dxp = 0; dxp < 2; ++dxp) {
                    int as = P1w + aimg * 1178 + (2 * i + ady + s) * 84 + (2 * jx + dxp) * 6 + 8 * g;
                    int ai = as >> 1;
                    union { int4 i4; short8 s8; } a;
                    a.i4.x = p1i[ai];     a.i4.y = p1i[ai + 1];
                    a.i4.z = p1i[ai + 2]; a.i4.w = p1i[ai + 3];
                    floatx4* acc = dxp == 0 ? &a0 : &a1;
                    *acc = __builtin_amdgcn_mfma_f32_16x16x32_bf16(a.s8, Breg[s], *acc, 0, 0, 0);
                }
            }
            if (g == 0) {   // C rows 0..3 = (img=rg&1, dy=rg>>1); dy-max is IN-LANE
                #pragma unroll
                for (int im = 0; im < 2; ++im) {
                    float v = fmaxf(fmaxf(a0[im], a1[im]), fmaxf(a0[im + 2], a1[im + 2]));
                    sh[P2w + im * 424 + cn * 25 + i * 5 + jx] = (short)f2bf(fmaxf(v, 0.f));
                }
            }
        }
    }

    // ---- fc1 via MFMA (per-wave): K=400 (13 steps), N=120 (8 tiles) ----
    for (int nt = 0; nt < 8; ++nt) {
        floatx4 acc = {0.f,0.f,0.f,0.f};
        int n = nt * 16 + cn;
        const float* wrow = fw1 + (size_t)(n < 120 ? n : 119) * 400;
        for (int ks = 0; ks < 13; ++ks) {
            int kb = ks * 32 + 8 * g;
            short8 b = load_bf8t(wrow, kb, 400);
            short8 a = *(const short8*)(sh + P2w + (cn & 1) * 424 + kb);
            acc = __builtin_amdgcn_mfma_f32_16x16x32_bf16(a, b, acc, 0, 0, 0);
        }
        if (g == 0 && n < 120) {
            sh[H1w + n]       = (short)f2bf(fmaxf(acc[0], 0.f));   // img0 (row 0)
            sh[H1w + 136 + n] = (short)f2bf(fmaxf(acc[1], 0.f));   // img1 (row 1)
        }
    }

    // ---- fc2 via MFMA (per-wave): K=120 (4 steps), N=84 (6 tiles) ----
    for (int nt = 0; nt < 6; ++nt) {
        floatx4 acc = {0.f,0.f,0.f,0.f};
        int n = nt * 16 + cn;
        const float* wrow = fw2 + (size_t)(n < 84 ? n : 83) * 120;
        for (int ks = 0; ks < 4; ++ks) {
            int kb = ks * 32 + 8 * g;
            short8 b = load_bf8t(wrow, kb, 120);
            short8 a = *(const short8*)(sh + H1w + (cn & 1) * 136 + kb);
            acc = __builtin_amdgcn_mfma_f32_16x16x32_bf16(a, b, acc, 0, 0, 0);
        }
        if (g == 0 && n < 84) {
            sh[H2w + n]       = (short)f2bf(fmaxf(acc[0], 0.f));
            sh[H2w + 104 + n] = (short)f2bf(fmaxf(acc[1], 0.f));
        }
    }

    // ---- fc3 via MFMA (per-wave): K=84 (3 steps), N=10 + bias ----
    {
        floatx4 acc = {0.f,0.f,0.f,0.f};
        int n = cn;
        const float* wrow = fc3w + (size_t)(n < 10 ? n : 9) * 84;
        for (int ks = 0; ks < 3; ++ks) {
            int kb = ks * 32 + 8 * g;
            short8 b = load_bf8t(wrow, kb, 84);
            short8 a = *(const short8*)(sh + H2w + (cn & 1) * 104 + kb);
            acc = __builtin_amdgcn_mfma_f32_16x16x32_bf16(a, b, acc, 0, 0, 0);
        }
        if (g == 0 && n < 10) {
            float bias = fc3b[n];
            sf[LOGf + n]      = acc[0] + bias;   // img0
            sf[LOGf + 12 + n] = acc[1] + bias;   // img1
        }
    }

    // ---- softmax: lanes 0,1 handle the wave's 2 images ----
    if (lane < 2) {
        const float* lg = sf + LOGf + lane * 12;
        float mx = lg[0];
        #pragma unroll
        for (int n = 1; n < 10; ++n) mx = fmaxf(mx, lg[n]);
        float e[10]; float sum = 0.f;
        #pragma unroll
        for (int n = 0; n < 10; ++n) { e[n] = expf(lg[n] - mx); sum += e[n]; }
        float inv = 1.f / sum;
        float* op = out + (imgbase + lane) * 10;
        #pragma unroll
        for (int n = 0; n < 10; ++n) op[n] = e[n] * inv;
    }
}

extern "C" void kernel_launch(void* const* d_in, const int* in_sizes, int n_in,
                              void* d_out, int out_size, void* d_ws, size_t ws_size,
                              hipStream_t stream) {
    const float* x    = (const float*)d_in[0];
    const float* w1   = (const float*)d_in[1];
    const float* w2   = (const float*)d_in[2];
    const float* fw1  = (const float*)d_in[3];
    const float* fw2  = (const float*)d_in[4];
    const float* fc3w = (const float*)d_in[5];
    const float* fc3b = (const float*)d_in[6];
    float* outp = (float*)d_out;

    dim3 grid(16384 / 8), block(TH);
    hipLaunchKernelGGL(lenet_kernel, grid, block, 0, stream,
                       x, w1, w2, fw1, fw2, fc3w, fc3b, outp);
}

// Round 13
// 89.726 us; speedup vs baseline: 1.8011x; 1.8011x over previous
//
#include <hip/hip_runtime.h>
#include <hip/hip_fp16.h>
#include <math.h>

#define TH 256

typedef __attribute__((ext_vector_type(8))) short short8;
typedef __attribute__((ext_vector_type(4))) float floatx4;

// ---- LDS layout (shorts), 23248 sh = 46496 B -> 3 blocks/CU (= achieved occupancy) ----
// P1 (shared)            @ 0      : 8 img * 1178
// X  (PER-WAVE, 2 imgs)  @ 9424 + wid*2184 : 2*1090   (dead after conv1)
//   aliases after the post-conv1 barrier (shared): P2 @9424 (8*424),
//   H1 @12816 (8*136), H2 @13904 (8*104), LOG floats @7368 (sh 14736..14928)
// BT (shared w2)         @ 18160  : 16 oc * 168
// W1B (PER-WAVE bcast)   @ 20848 + wid*600 : 150 half2
#define P1_S   0
#define X0_S   9424
#define WVX    2184
#define P2_S   9424
#define H1_S   12816
#define H2_S   13904
#define LOG_F  7368
#define BT_S   18160
#define W1U_0  10424      // uint index of wave-0 W1B
#define W1U_W  300        // uint stride per wave
#define LDS_F  11624      // floats total = 46496 B

static __device__ __forceinline__ unsigned short f2bf(float x) {
    union { float f; unsigned u; } v; v.f = x;
    return (unsigned short)((v.u + 0x7FFFu + ((v.u >> 16) & 1u)) >> 16);   // RNE
}
static __device__ __forceinline__ __half2 uash2(unsigned u) {
    union { unsigned u; __half2 h; } v; v.u = u; return v.h;
}
static __device__ __forceinline__ unsigned bfpack(unsigned hi, unsigned lo) {
    return __builtin_amdgcn_perm(hi, lo, 0x07060302u);   // 1x v_perm_b32 truncation
}
// weights row[kb..kb+7] -> bf16 frag; per-quad clamp keeps loads in bounds at the
// K tail (matching A slots are zero-padded).
static __device__ __forceinline__ short8 load_bf8t(const float* row, int kb, int K) {
    int b0 = (kb + 4 <= K) ? kb : (K - 8);
    int b1 = (kb + 8 <= K) ? (kb + 4) : (K - 8);
    uint4 w0 = *(const uint4*)(row + b0);
    uint4 w1 = *(const uint4*)(row + b1);
    union { int4 i; short8 s; } r;
    r.i.x = (int)bfpack(w0.y, w0.x);
    r.i.y = (int)bfpack(w0.w, w0.z);
    r.i.z = (int)bfpack(w1.y, w1.x);
    r.i.w = (int)bfpack(w1.w, w1.z);
    return r.s;
}

// NOTE: no min-waves arg (round 3: VGPR clamp -> scratch spill storm).
__global__ __launch_bounds__(TH) void lenet_kernel(
    const float* __restrict__ x,
    const float* __restrict__ w1,
    const float* __restrict__ w2g,
    const float* __restrict__ fw1,
    const float* __restrict__ fw2,
    const float* __restrict__ fc3w,
    const float* __restrict__ fc3b,
    float* __restrict__ out)
{
    __shared__ __align__(16) float sf[LDS_F];
    short* sh = (short*)sf;
    unsigned* su = (unsigned*)sf;
    const int* p1i = (const int*)sf;

    const int tid  = threadIdx.x;
    const int blk  = blockIdx.x;
    const int lane = tid & 63;
    const int wid  = tid >> 6;
    const int g    = lane >> 4;     // k-group selector of MFMA frags
    const int cn   = lane & 15;     // row(A)/col(B) selector
    const int pr   = cn & 7;        // img row (conv2: rows 8..15 = dy=1 of imgs 0..7)
    const int dyr  = cn >> 3;       // conv2 pool-row packed into M

    const int Xw   = X0_S + wid * WVX;          // per-wave x base (shorts)
    const int W1u  = W1U_0 + wid * W1U_W;       // per-wave w1-broadcast base (uints)
    const size_t imgbase = (size_t)blk * 8 + (size_t)wid * 2;

    // ---- prefetch BOTH of this wave's images into registers ----
    float4 xreg[8];
    {
        const float4* xg = (const float4*)(x + imgbase * 1024);
        #pragma unroll
        for (int j = 0; j < 8; ++j) xreg[j] = xg[lane + j * 64];   // j<4: img0, j>=4: img1
    }

    // ---- cooperative BT (w2) staging: ordered for conv2 by the post-conv1 barrier ----
    for (int e = tid; e < 2560; e += TH) {
        int oc = e / 160, kk = e - oc * 160;
        int s = kk >> 5, r = kk & 31;
        float v = 0.f;
        if (r < 30) v = w2g[oc * 150 + (r % 6) * 25 + s * 5 + (r / 6)];
        sh[BT_S + oc * 168 + kk] = (short)f2bf(v);
    }
    // ---- per-wave w1 broadcast staging (wave-internal DS order; no barrier) ----
    for (int e = lane; e < 150; e += 64)
        ((__half2*)(su + W1u))[e] = __half2half2(__float2half(w1[e]));

    // ---- per-wave x staging: row stride 34 halfs (17 words, odd -> conflict-free) ----
    #pragma unroll
    for (int j = 0; j < 8; ++j) {
        int e = lane + (j & 3) * 64;
        float4 v = xreg[j];
        int y = e >> 3, k4 = e & 7;
        int off = Xw + (j >> 2) * 1090 + y * 34 + k4 * 4;
        *(__half2*)(sh + off)     = __floats2half2_rn(v.x, v.y);
        *(__half2*)(sh + off + 2) = __floats2half2_rn(v.z, v.w);
    }

    // ======== conv1 (packed fp16 VALU): per-wave, BARRIER-FREE ========
    // 336 tasks (2 imgs x 168) over 64 lanes = 6 passes
    for (int p = 0; p < 6; ++p) {
        int t = p * 64 + lane;
        if (t < 336) {
            int img = t / 168, r = t - img * 168;
            int c = r % 6, q = r / 6;
            int i = q >> 1, hf = q & 1;
            const __half2* wb = (const __half2*)(su + W1u) + c * 25;
            const int xbase = Xw + img * 1090 + hf * 14;

            __half2 acc0[7], acc1[7];
            #pragma unroll
            for (int j = 0; j < 7; ++j) { acc0[j] = uash2(0u); acc1[j] = uash2(0u); }
            __half2 wprev[5];
            #pragma unroll
            for (int tt = 0; tt < 6; ++tt) {
                unsigned u[9];
                const unsigned* rp = (const unsigned*)(sh + xbase + (2 * i + tt) * 34);
                #pragma unroll
                for (int qq = 0; qq < 9; ++qq) u[qq] = rp[qq];
                __half2 p0[9], p1[8];
                #pragma unroll
                for (int qq = 0; qq < 9; ++qq) p0[qq] = uash2(u[qq]);
                #pragma unroll
                for (int qq = 0; qq < 8; ++qq)
                    p1[qq] = uash2(__builtin_amdgcn_perm(u[qq + 1], u[qq], 0x05040302u));

                if (tt < 5) {
                    __half2 wc[5];
                    #pragma unroll
                    for (int kx = 0; kx < 5; ++kx) wc[kx] = wb[tt * 5 + kx];
                    #pragma unroll
                    for (int j = 0; j < 7; ++j) {
                        acc0[j] = __hfma2(p0[j],     wc[0], acc0[j]);
                        acc0[j] = __hfma2(p1[j],     wc[1], acc0[j]);
                        acc0[j] = __hfma2(p0[j + 1], wc[2], acc0[j]);
                        acc0[j] = __hfma2(p1[j + 1], wc[3], acc0[j]);
                        acc0[j] = __hfma2(p0[j + 2], wc[4], acc0[j]);
                    }
                    if (tt >= 1) {
                        #pragma unroll
                        for (int j = 0; j < 7; ++j) {
                            acc1[j] = __hfma2(p0[j],     wprev[0], acc1[j]);
                            acc1[j] = __hfma2(p1[j],     wprev[1], acc1[j]);
                            acc1[j] = __hfma2(p0[j + 1], wprev[2], acc1[j]);
                            acc1[j] = __hfma2(p1[j + 1], wprev[3], acc1[j]);
                            acc1[j] = __hfma2(p0[j + 2], wprev[4], acc1[j]);
                        }
                    }
                    #pragma unroll
                    for (int kx = 0; kx < 5; ++kx) wprev[kx] = wc[kx];
                } else {    // tt == 5: acc1 only, with w row 4 (in wprev)
                    #pragma unroll
                    for (int j = 0; j < 7; ++j) {
                        acc1[j] = __hfma2(p0[j],     wprev[0], acc1[j]);
                        acc1[j] = __hfma2(p1[j],     wprev[1], acc1[j]);
                        acc1[j] = __hfma2(p0[j + 1], wprev[2], acc1[j]);
                        acc1[j] = __hfma2(p1[j + 1], wprev[3], acc1[j]);
                        acc1[j] = __hfma2(p0[j + 2], wprev[4], acc1[j]);
                    }
                }
            }
            int gi = wid * 2 + img;
            short* dst = sh + P1_S + gi * 1178 + i * 84 + hf * 42 + c;
            #pragma unroll
            for (int j = 0; j < 7; ++j) {
                float a0l = __half2float(__low2half(acc0[j]));
                float a0h = __half2float(__high2half(acc0[j]));
                float a1l = __half2float(__low2half(acc1[j]));
                float a1h = __half2float(__high2half(acc1[j]));
                float v = fmaxf(fmaxf(fmaxf(a0l, a0h), fmaxf(a1l, a1h)), 0.f);
                dst[j * 6] = (short)f2bf(v);
            }
        }
    }
    __syncthreads();   // the FIRST barrier: p1 complete (all waves) + BT visible

    // ===== conv2 via MFMA, dy-packed: M = img(8) x pool-row dy(2), N=16 oc, K=5x32 =====
    {
        short8 Breg[5];
        #pragma unroll
        for (int s = 0; s < 5; ++s)
            Breg[s] = *(const short8*)(sh + BT_S + cn * 168 + s * 32 + 8 * g);

        for (int e = tid; e < 8 * 24; e += TH) {        // p2 k-pad zeros [400,424)
            int im = e / 24;
            sh[P2_S + im * 424 + 400 + (e - im * 24)] = 0;
        }

        for (int w = wid; w < 25; w += 4) {             // pool windows (i,jx)
            int i = w / 5, jx = w - 5 * i;
            floatx4 a0 = {0.f,0.f,0.f,0.f}, a1 = {0.f,0.f,0.f,0.f};
            #pragma unroll
            for (int s = 0; s < 5; ++s) {
                #pragma unroll
                for (int dxp = 0; dxp < 2; ++dxp) {
                    int as = pr * 1178 + (2 * i + dyr + s) * 84 + (2 * jx + dxp) * 6 + 8 * g;
                    int ai = as >> 1;               // 4B-aligned
                    union { int4 i4; short8 s8; } a;
                    a.i4.x = p1i[ai];     a.i4.y = p1i[ai + 1];
                    a.i4.z = p1i[ai + 2]; a.i4.w = p1i[ai + 3];
                    floatx4* acc = dxp == 0 ? &a0 : &a1;
                    *acc = __builtin_amdgcn_mfma_f32_16x16x32_bf16(a.s8, Breg[s], *acc, 0, 0, 0);
                }
            }
            // pool: in-lane dx max, cross-row dy max (row r vs r+8 = lane xor 32)
            #pragma unroll
            for (int rg = 0; rg < 4; ++rg) {
                float v = fmaxf(a0[rg], a1[rg]);
                v = fmaxf(v, __shfl_xor(v, 32));
                if (g < 2) {
                    int im = 4 * g + rg;
                    sh[P2_S + im * 424 + cn * 25 + i * 5 + jx] = (short)f2bf(fmaxf(v, 0.f));
                }
            }
        }
    }
    __syncthreads();

    // ================= fc1 via MFMA: K=400(13 steps), N=120(8 tiles) =================
    {
        for (int e = tid; e < 8 * 16; e += TH) {        // h1 pad zeros [120,136)
            int im = e >> 4;
            sh[H1_S + im * 136 + 120 + (e & 15)] = 0;
        }
        for (int nt = wid; nt < 8; nt += 4) {
            floatx4 acc = {0.f,0.f,0.f,0.f};
            int n = nt * 16 + cn;
            const float* wrow = fw1 + (size_t)(n < 120 ? n : 119) * 400;
            for (int ks = 0; ks < 13; ++ks) {
                int kb = ks * 32 + 8 * g;
                short8 b = load_bf8t(wrow, kb, 400);
                short8 a = *(const short8*)(sh + P2_S + pr * 424 + kb);
                acc = __builtin_amdgcn_mfma_f32_16x16x32_bf16(a, b, acc, 0, 0, 0);
            }
            if (g < 2 && n < 120) {
                #pragma unroll
                for (int rg = 0; rg < 4; ++rg)
                    sh[H1_S + (4 * g + rg) * 136 + n] = (short)f2bf(fmaxf(acc[rg], 0.f));
            }
        }
    }
    __syncthreads();

    // ================= fc2 via MFMA: K=120(4 steps), N=84(6 tiles) =================
    {
        for (int e = tid; e < 8 * 20; e += TH) {        // h2 pad zeros [84,104)
            int im = e / 20;
            sh[H2_S + im * 104 + 84 + (e - im * 20)] = 0;
        }
        for (int nt = wid; nt < 6; nt += 4) {
            floatx4 acc = {0.f,0.f,0.f,0.f};
            int n = nt * 16 + cn;
            const float* wrow = fw2 + (size_t)(n < 84 ? n : 83) * 120;
            for (int ks = 0; ks < 4; ++ks) {
                int kb = ks * 32 + 8 * g;
                short8 b = load_bf8t(wrow, kb, 120);
                short8 a = *(const short8*)(sh + H1_S + pr * 136 + kb);
                acc = __builtin_amdgcn_mfma_f32_16x16x32_bf16(a, b, acc, 0, 0, 0);
            }
            if (g < 2 && n < 84) {
                #pragma unroll
                for (int rg = 0; rg < 4; ++rg)
                    sh[H2_S + (4 * g + rg) * 104 + n] = (short)f2bf(fmaxf(acc[rg], 0.f));
            }
        }
    }
    __syncthreads();

    // ================= fc3 via MFMA: K=84(3 steps), N=10 + bias =================
    if (wid == 0) {
        floatx4 acc = {0.f,0.f,0.f,0.f};
        int n = cn;
        const float* wrow = fc3w + (size_t)(n < 10 ? n : 9) * 84;
        for (int ks = 0; ks < 3; ++ks) {
            int kb = ks * 32 + 8 * g;
            short8 b = load_bf8t(wrow, kb, 84);
            short8 a = *(const short8*)(sh + H2_S + pr * 104 + kb);
            acc = __builtin_amdgcn_mfma_f32_16x16x32_bf16(a, b, acc, 0, 0, 0);
        }
        if (g < 2 && n < 10) {
            float bias = fc3b[n];
            #pragma unroll
            for (int rg = 0; rg < 4; ++rg)
                sf[LOG_F + (4 * g + rg) * 12 + n] = acc[rg] + bias;
        }
    }
    __syncthreads();

    // ================= softmax, one thread per image =================
    if (tid < 8) {
        const float* lg = sf + LOG_F + tid * 12;
        float mx = lg[0];
        #pragma unroll
        for (int n = 1; n < 10; ++n) mx = fmaxf(mx, lg[n]);
        float e[10]; float sum = 0.f;
        #pragma unroll
        for (int n = 0; n < 10; ++n) { e[n] = expf(lg[n] - mx); sum += e[n]; }
        float inv = 1.f / sum;
        float* op = out + ((size_t)blk * 8 + tid) * 10;
        #pragma unroll
        for (int n = 0; n < 10; ++n) op[n] = e[n] * inv;
    }
}

extern "C" void kernel_launch(void* const* d_in, const int* in_sizes, int n_in,
                              void* d_out, int out_size, void* d_ws, size_t ws_size,
                              hipStream_t stream) {
    const float* x    = (const float*)d_in[0];
    const float* w1   = (const float*)d_in[1];
    const float* w2   = (const float*)d_in[2];
    const float* fw1  = (const float*)d_in[3];
    const float* fw2  = (const float*)d_in[4];
    const float* fc3w = (const float*)d_in[5];
    const float* fc3b = (const float*)d_in[6];
    float* outp = (float*)d_out;

    dim3 grid(16384 / 8), block(TH);
    hipLaunchKernelGGL(lenet_kernel, grid, block, 0, stream,
                       x, w1, w2, fw1, fw2, fc3w, fc3b, outp);
}